// Round 3
// baseline (181.401 us; speedup 1.0000x reference)
//
#include <hip/hip_runtime.h>
#include <math.h>

#define SEQ 512
#define FDIM 64
#define D 8

__global__ __launch_bounds__(512, 4) void hybrid_attn_kernel(
    const float* __restrict__ state,    // [B,S,F]
    const float* __restrict__ proj_w,   // [F,D]
    const float* __restrict__ proj_b,   // [D]
    const float* __restrict__ rotation, // [D,D]
    const float* __restrict__ entangle, // [D,D]
    const float* __restrict__ w1,       // [D,32]
    const float* __restrict__ b1,       // [32]
    const float* __restrict__ w2,       // [32,16]
    const float* __restrict__ b2,       // [16]
    const float* __restrict__ w3,       // [16,1]
    const float* __restrict__ b3,       // [1]
    float* __restrict__ out)            // [B,S]
{
    // Dedicated, non-aliased LDS regions. ~65 KB total -> 2 blocks/CU.
    __shared__ __align__(16) float s_proj[SEQ * D];   // 16 KB  (V matrix)
    __shared__ __align__(16) float s_k[SEQ * D];      // 16 KB
    __shared__ __align__(16) float s_q[SEQ * D];      // 16 KB  (pre-scaled q)
    __shared__ __align__(16) float s_mrg[256 * 12];   // 12 KB  (merge: acc[8], l, m)
    __shared__ __align__(16) float s_pw[FDIM][D];     // 2 KB
    __shared__ float s_rot[D * D];
    __shared__ float s_ent[D * D];
    __shared__ float s_pb[D];
    __shared__ float s_w1[D * 32];
    __shared__ float s_b1[32];
    __shared__ float s_w2[32 * 16];
    __shared__ float s_b2[16];
    __shared__ float s_w3[16];
    __shared__ float s_b3[1];

    const int bb   = blockIdx.x;
    const int b    = bb >> 1;      // batch
    const int half = bb & 1;       // which 256 q-rows this block owns
    const int tid  = threadIdx.x;

    // ---- stage small weights into LDS ----
    if (tid < FDIM * D) ((float*)s_pw)[tid] = proj_w[tid];
    if (tid < D * D) {
        s_rot[tid] = rotation[tid];
        s_ent[tid] = entangle[tid];
    }
    if (tid < D)       s_pb[tid] = proj_b[tid];
    if (tid < D * 32)  s_w1[tid] = w1[tid];
    if (tid < 32)      s_b1[tid] = b1[tid];
    if (tid < 32 * 16) s_w2[tid] = w2[tid];
    if (tid < 16) { s_b2[tid] = b2[tid]; s_w3[tid] = w3[tid]; }
    if (tid == 0)      s_b3[0] = b3[0];
    __syncthreads();

    // ---- phase 1 (verified): one thread per row; proj, q (pre-scaled), k ----
    {
        const int r = tid;
        float pj[D];
        #pragma unroll
        for (int j = 0; j < D; j++) pj[j] = s_pb[j];

        const float4* srp = (const float4*)(state + ((size_t)b * SEQ + r) * FDIM);
        #pragma unroll
        for (int c = 0; c < FDIM / 4; c++) {
            float4 v = srp[c];
            float vs[4] = {v.x, v.y, v.z, v.w};
            #pragma unroll
            for (int u = 0; u < 4; u++) {
                #pragma unroll
                for (int j = 0; j < D; j++) pj[j] += vs[u] * s_pw[c * 4 + u][j];
            }
        }

        const float QS = 0.35355339059327373f;  // 1/sqrt(8) folded into q
        float qv[D], kv[D];
        #pragma unroll
        for (int j = 0; j < D; j++) {
            float aq = 0.f, ak = 0.f;
            #pragma unroll
            for (int i = 0; i < D; i++) {
                aq += pj[i] * s_rot[i * D + j];
                ak += pj[i] * s_ent[i * D + j];
            }
            qv[j] = aq * QS;
            kv[j] = ak;
        }

        float4* dp = (float4*)(s_proj + r * D);
        dp[0] = make_float4(pj[0], pj[1], pj[2], pj[3]);
        dp[1] = make_float4(pj[4], pj[5], pj[6], pj[7]);
        float4* dq = (float4*)(s_q + r * D);
        dq[0] = make_float4(qv[0], qv[1], qv[2], qv[3]);
        dq[1] = make_float4(qv[4], qv[5], qv[6], qv[7]);
        float4* dk = (float4*)(s_k + r * D);
        dk[0] = make_float4(kv[0], kv[1], kv[2], kv[3]);
        dk[1] = make_float4(kv[4], kv[5], kv[6], kv[7]);
    }
    __syncthreads();

    // ---- phase 2: exact-max two-pass softmax, 2 threads per q-row (t split) ----
    const int p   = tid & 255;            // row index within this block's half
    const int row = half * 256 + p;       // global q-row
    const int th  = tid >> 8;             // t-half 0/1

    float q[D];
    {
        const float4* qp = (const float4*)(s_q + row * D);
        float4 x0 = qp[0], x1 = qp[1];
        q[0]=x0.x; q[1]=x0.y; q[2]=x0.z; q[3]=x0.w;
        q[4]=x1.x; q[5]=x1.y; q[6]=x1.z; q[7]=x1.w;
    }

    const float* kp = s_k    + th * 256 * D;
    const float* vp = s_proj + th * 256 * D;

    // pass 1: exact local max over this thread's 256 t's
    float m = -1e30f;
    #pragma unroll 4
    for (int t = 0; t < 256; t++) {
        const float4* kt = (const float4*)(kp + t * D);  // wave-uniform -> broadcast
        float4 k0 = kt[0], k1 = kt[1];
        float s = q[0]*k0.x + q[1]*k0.y + q[2]*k0.z + q[3]*k0.w
                + q[4]*k1.x + q[5]*k1.y + q[6]*k1.z + q[7]*k1.w;
        m = fmaxf(m, s);
    }

    // pass 2: exp + weighted V accumulate
    float l = 0.f;
    float acc[D] = {0.f,0.f,0.f,0.f,0.f,0.f,0.f,0.f};
    #pragma unroll 4
    for (int t = 0; t < 256; t++) {
        const float4* kt = (const float4*)(kp + t * D);
        float4 k0 = kt[0], k1 = kt[1];
        const float4* vt = (const float4*)(vp + t * D);
        float4 v0 = vt[0], v1 = vt[1];
        float s = q[0]*k0.x + q[1]*k0.y + q[2]*k0.z + q[3]*k0.w
                + q[4]*k1.x + q[5]*k1.y + q[6]*k1.z + q[7]*k1.w;
        float e = __expf(s - m);
        l += e;
        acc[0] += e*v0.x; acc[1] += e*v0.y; acc[2] += e*v0.z; acc[3] += e*v0.w;
        acc[4] += e*v1.x; acc[5] += e*v1.y; acc[6] += e*v1.z; acc[7] += e*v1.w;
    }
    __syncthreads();

    // ---- flash-combine the two t-halves: th==1 publishes, th==0 merges ----
    if (th) {
        float* dd = s_mrg + p * 12;
        ((float4*)dd)[0] = make_float4(acc[0], acc[1], acc[2], acc[3]);
        ((float4*)dd)[1] = make_float4(acc[4], acc[5], acc[6], acc[7]);
        dd[8] = l;
        dd[9] = m;
    }
    __syncthreads();

    if (!th) {
        const float* ss = s_mrg + p * 12;
        float4 u0 = ((const float4*)ss)[0], u1 = ((const float4*)ss)[1];
        const float lR = ss[8];
        const float mR = ss[9];

        const float M  = fmaxf(m, mR);
        const float a0 = __expf(m  - M);   // scale for this thread's partials
        const float a1 = __expf(mR - M);   // scale for the other half's partials

        l = l * a0 + lR * a1;
        acc[0] = acc[0]*a0 + u0.x*a1; acc[1] = acc[1]*a0 + u0.y*a1;
        acc[2] = acc[2]*a0 + u0.z*a1; acc[3] = acc[3]*a0 + u0.w*a1;
        acc[4] = acc[4]*a0 + u1.x*a1; acc[5] = acc[5]*a0 + u1.y*a1;
        acc[6] = acc[6]*a0 + u1.z*a1; acc[7] = acc[7]*a0 + u1.w*a1;

        const float inv_l = 1.0f / l;
        float attn[D];
        #pragma unroll
        for (int j = 0; j < D; j++) attn[j] = acc[j] * inv_l;

        // ---- MLP head d -> 32 -> 16 -> 1 ----
        float h1[32];
        #pragma unroll
        for (int j = 0; j < 32; j++) {
            float a = s_b1[j];
            #pragma unroll
            for (int i = 0; i < D; i++) a += attn[i] * s_w1[i * 32 + j];
            h1[j] = fmaxf(a, 0.f);
        }
        float h2[16];
        #pragma unroll
        for (int j = 0; j < 16; j++) {
            float a = s_b2[j];
            #pragma unroll
            for (int i = 0; i < 32; i++) a += h1[i] * s_w2[i * 16 + j];
            h2[j] = fmaxf(a, 0.f);
        }
        float o = s_b3[0];
        #pragma unroll
        for (int i = 0; i < 16; i++) o += h2[i] * s_w3[i];

        out[(size_t)b * SEQ + row] = o;
    }
}

extern "C" void kernel_launch(void* const* d_in, const int* in_sizes, int n_in,
                              void* d_out, int out_size, void* d_ws, size_t ws_size,
                              hipStream_t stream) {
    const float* state    = (const float*)d_in[0];
    const float* proj_w   = (const float*)d_in[1];
    const float* proj_b   = (const float*)d_in[2];
    const float* rotation = (const float*)d_in[3];
    const float* entangle = (const float*)d_in[4];
    const float* w1       = (const float*)d_in[5];
    const float* b1       = (const float*)d_in[6];
    const float* w2       = (const float*)d_in[7];
    const float* b2       = (const float*)d_in[8];
    const float* w3       = (const float*)d_in[9];
    const float* b3       = (const float*)d_in[10];
    float* out = (float*)d_out;

    const int B = in_sizes[0] / (SEQ * FDIM);  // 256
    hybrid_attn_kernel<<<B * 2, 512, 0, stream>>>(
        state, proj_w, proj_b, rotation, entangle,
        w1, b1, w2, b2, w3, b3, out);
}